// Round 1
// baseline (190.858 us; speedup 1.0000x reference)
//
#include <hip/hip_runtime.h>

// Tricubic B-spline evaluation, p=3, NC=64 per axis, DOUT=3, open-uniform knots.
// Knots: t[i] = clamp((i-3)/61, 0, 1) for i in [0,68). Matches
// np.linspace(0,1,62) within 1 ulp; spline continuity makes span-boundary
// rounding differences negligible (<<1e-3 vs 3.8e-2 threshold).

typedef float vfloat4 __attribute__((ext_vector_type(4)));

__device__ __forceinline__ float knotv(int i, float inv) {
  float v = (float)(i - 3) * inv;
  return fminf(fmaxf(v, 0.0f), 1.0f);
}

// Cox-de Boor basis (NURBS book A2.2). Returns span k (in [3,63]) and the
// p+1 = 4 nonzero basis values N[0..3] for global indices k-3..k.
__device__ __forceinline__ void basis4(float x, float inv, int nseg, int& k,
                                       float N[4]) {
  float xc = fminf(fmaxf(x, 0.0f), 1.0f);
  int j = (int)floorf(xc * (float)nseg);
  j = j > nseg - 1 ? nseg - 1 : (j < 0 ? 0 : j);
  k = j + 3;
  float left[4], right[4];
  N[0] = 1.0f;
#pragma unroll
  for (int jj = 1; jj <= 3; ++jj) {
    left[jj] = xc - knotv(k + 1 - jj, inv);
    right[jj] = knotv(k + jj, inv) - xc;
    float saved = 0.0f;
#pragma unroll
    for (int r = 0; r < jj; ++r) {
      float temp = N[r] / (right[r + 1] + left[jj - r]);
      N[r] = saved + right[r + 1] * temp;
      saved = left[jj - r] * temp;
    }
    N[jj] = saved;
  }
}

__global__ __launch_bounds__(256) void spline_eval_kernel(
    const float* __restrict__ q, const float* __restrict__ cp,
    float* __restrict__ out, int nq, int nc) {
  int i = blockIdx.x * 256 + threadIdx.x;
  if (i >= nq) return;

  float xyz[3];
  __builtin_memcpy(xyz, q + 3 * (size_t)i, 12);

  const int nseg = nc - 3;              // 61 interior segments
  const float inv = 1.0f / (float)nseg; // 1/61

  int kx, ky, kz;
  float Nx[4], Ny[4], Nz[4];
  basis4(xyz[0], inv, nseg, kx, Nx);
  basis4(xyz[1], inv, nseg, ky, Ny);
  basis4(xyz[2], inv, nseg, kz, Nz);

  int ix0 = kx - 3, iy0 = ky - 3, iz0 = kz - 3;

  float accx = 0.0f, accy = 0.0f, accz = 0.0f;
#pragma unroll 1
  for (int c = 0; c < 4; ++c) {
    int zb = (iz0 + c) * nc;
#pragma unroll
    for (int b = 0; b < 4; ++b) {
      float w = Ny[b] * Nz[c];
      // 4 x-neighbors are contiguous: 12 floats = 48 B starting here.
      const float* row = cp + 3 * (size_t)(ix0 + nc * (iy0 + b + zb));
      vfloat4 f0, f1, f2;  // align-4 16B loads -> global_load_dwordx4
      __builtin_memcpy(&f0, row + 0, 16);
      __builtin_memcpy(&f1, row + 4, 16);
      __builtin_memcpy(&f2, row + 8, 16);
      // f0={x0,y0,z0,x1} f1={y1,z1,x2,y2} f2={z2,x3,y3,z3}
      accx += w * (Nx[0] * f0.x + Nx[1] * f0.w + Nx[2] * f1.z + Nx[3] * f2.y);
      accy += w * (Nx[0] * f0.y + Nx[1] * f1.x + Nx[2] * f1.w + Nx[3] * f2.z);
      accz += w * (Nx[0] * f0.z + Nx[1] * f1.y + Nx[2] * f2.x + Nx[3] * f2.w);
    }
  }

  float o[3] = {accx, accy, accz};
  __builtin_memcpy(out + 3 * (size_t)i, o, 12);
}

extern "C" void kernel_launch(void* const* d_in, const int* in_sizes, int n_in,
                              void* d_out, int out_size, void* d_ws,
                              size_t ws_size, hipStream_t stream) {
  const float* queries = (const float*)d_in[0];
  const float* control = (const float*)d_in[1];
  float* out = (float*)d_out;

  int nq = in_sizes[0] / 3;  // 1,000,000
  // in_sizes[1] = nc^3 * 3 -> nc = 64 (known); derive robustly:
  int nc = 64;

  int blocks = (nq + 255) / 256;
  spline_eval_kernel<<<blocks, 256, 0, stream>>>(queries, control, out, nq, nc);
}